// Round 8
// baseline (332.290 us; speedup 1.0000x reference)
//
#include <hip/hip_runtime.h>

typedef __bf16 bf16;
typedef __bf16 bf16x4 __attribute__((ext_vector_type(4)));
typedef __bf16 bf16x8 __attribute__((ext_vector_type(8)));
typedef float f32x4 __attribute__((ext_vector_type(4)));

#define LOG2E 1.4426950408889634f
// folded into Q at pack time: score_in_log2_domain = (q.k) * 0.125 * LOG2E
#define QSCALE (0.125f * LOG2E)

__device__ __forceinline__ void gl_lds16(const bf16* g, bf16* l) {
  __builtin_amdgcn_global_load_lds(
      (const __attribute__((address_space(1))) void*)g,
      (__attribute__((address_space(3))) void*)l, 16, 0, 0);
}

#define MFMA16 __builtin_amdgcn_mfma_f32_16x16x32_bf16

// ---------------- pack kernels ----------------

__global__ void pack_x_kernel(const float* __restrict__ x, bf16* __restrict__ xb, int n) {
  int i = (blockIdx.x * 256 + threadIdx.x) * 4;
  if (i >= n) return;
  float4 v = *(const float4*)(x + i);
  xb[i + 0] = (bf16)v.x;
  xb[i + 1] = (bf16)v.y;
  xb[i + 2] = (bf16)v.z;
  xb[i + 3] = (bf16)v.w;
}

__global__ void pack_wqkv_kernel(const float* __restrict__ wq, const float* __restrict__ wk,
                                 const float* __restrict__ wv, bf16* __restrict__ wT) {
  __shared__ float tile[64][65];
  const int et = blockIdx.x;
  const int h  = blockIdx.y;
  const int p  = blockIdx.z;
  const float* src = (p == 0 ? wq : (p == 1 ? wk : wv)) + (size_t)h * 1024 * 64;
  const int tx = threadIdx.x & 63;
  const int ty = threadIdx.x >> 6;
  const int e0 = et * 64;
#pragma unroll
  for (int i = 0; i < 64; i += 4)
    tile[i + ty][tx] = src[(size_t)(e0 + i + ty) * 64 + tx];
  __syncthreads();
#pragma unroll
  for (int i = 0; i < 64; i += 4) {
    int d = i + ty;
    wT[((size_t)p * 1024 + h * 64 + d) * 1024 + e0 + tx] = (bf16)tile[tx][d];
  }
}

__global__ void pack_wproj_kernel(const float* __restrict__ wp, bf16* __restrict__ wT) {
  __shared__ float tile[64][65];
  const int ot = blockIdx.x, it = blockIdx.y;
  const int tx = threadIdx.x & 63;
  const int ty = threadIdx.x >> 6;
#pragma unroll
  for (int i = 0; i < 64; i += 4)
    tile[i + ty][tx] = wp[(size_t)(it * 64 + i + ty) * 1024 + ot * 64 + tx];
  __syncthreads();
#pragma unroll
  for (int i = 0; i < 64; i += 4) {
    int o = i + ty;
    wT[((size_t)ot * 64 + o) * 1024 + it * 64 + tx] = (bf16)tile[tx][o];
  }
}

// ---------------- GEMM: C[M,N] = A[M,K] * Bt[N,K]^T ----------------
template <int EPI>
__global__ __launch_bounds__(256, 2)
void gemm_bt(const bf16* __restrict__ A, const bf16* __restrict__ Bt,
             int M, int N, int K,
             bf16* qb, bf16* kb, bf16* vtb,
             const float* bq, const float* bk, const float* bv,
             float* outf, const float* bias) {
  __shared__ bf16 As[2][128 * 32];
  __shared__ bf16 Bs[2][128 * 32];
  const int tid = threadIdx.x;
  const int lane = tid & 63;
  const int w = tid >> 6;
  const int wm = w >> 1, wn = w & 1;
  const int m0 = blockIdx.y * 128, n0 = blockIdx.x * 128;
  const int r = tid >> 2;
  const int c = tid & 3;
  const int lr = lane & 15, lg = lane >> 4;

  f32x4 acc[4][4] = {};
  const bf16* Ar0 = A + (size_t)(m0 + r) * K + c * 8;
  const bf16* Ar1 = A + (size_t)(m0 + 64 + r) * K + c * 8;
  const bf16* Br0 = Bt + (size_t)(n0 + r) * K + c * 8;
  const bf16* Br1 = Bt + (size_t)(n0 + 64 + r) * K + c * 8;

#define STAGE(BUF, K0)                           \
  do {                                           \
    gl_lds16(Ar0 + (K0), &As[BUF][w * 512]);     \
    gl_lds16(Ar1 + (K0), &As[BUF][2048 + w * 512]); \
    gl_lds16(Br0 + (K0), &Bs[BUF][w * 512]);     \
    gl_lds16(Br1 + (K0), &Bs[BUF][2048 + w * 512]); \
  } while (0)

  STAGE(0, 0);
  int cur = 0;
  for (int k0 = 0; k0 < K; k0 += 32, cur ^= 1) {
    __syncthreads();
    if (k0 + 32 < K) STAGE(cur ^ 1, k0 + 32);
    bf16x8 af[4], bfr[4];
#pragma unroll
    for (int m = 0; m < 4; ++m)
      af[m] = *(const bf16x8*)&As[cur][(wm * 64 + m * 16 + lr) * 32 + lg * 8];
#pragma unroll
    for (int n = 0; n < 4; ++n)
      bfr[n] = *(const bf16x8*)&Bs[cur][(wn * 64 + n * 16 + lr) * 32 + lg * 8];
#pragma unroll
    for (int m = 0; m < 4; ++m)
#pragma unroll
      for (int n = 0; n < 4; ++n)
        acc[m][n] = MFMA16(af[m], bfr[n], acc[m][n], 0, 0, 0);
  }
#undef STAGE

#pragma unroll
  for (int m = 0; m < 4; ++m) {
    const int rowb = m0 + wm * 64 + m * 16 + lg * 4;
#pragma unroll
    for (int n = 0; n < 4; ++n) {
      const int col = n0 + wn * 64 + n * 16 + lr;
#pragma unroll
      for (int rr = 0; rr < 4; ++rr) {
        float v = acc[m][n][rr];
        const int rw = rowb + rr;
        if (EPI == 0) {
          const int p = col >> 10, rem = col & 1023;
          const int hh = rem >> 6, d = rem & 63;
          const int b = rw >> 11, s = rw & 2047;
          const size_t bhi = (size_t)(b * 16 + hh);
          if (p == 0)      qb[(bhi * 2048 + s) * 64 + d] = (bf16)((v + bq[rem]) * QSCALE);
          else if (p == 1) kb[(bhi * 2048 + s) * 64 + d] = (bf16)(v + bk[rem]);
          else             vtb[(bhi * 64 + d) * 2048 + s] = (bf16)(v + bv[rem]);
        } else {
          outf[(size_t)rw * N + col] = v + bias[col];
        }
      }
    }
  }
}

// ---------------- EXPERIMENTAL: LDS-staged attention (A/B candidate) -------
// Writes opart/lpart but is fully OVERWRITTEN by the proven attn_kernel that
// runs after it — this dispatch exists to get timing/counters for the staged
// structure. Round-7 version + paL zero-init + sched_barrier after lgkmcnt.
__global__ __launch_bounds__(256, 3)
void attn_stage_kernel(const bf16* __restrict__ qb, const bf16* __restrict__ kb,
                       const bf16* __restrict__ vtb,
                       bf16* __restrict__ opart, float* __restrict__ lpart) {
  __shared__ bf16 Ks[2][64 * 64];
  __shared__ bf16 Vs[2][64 * 64];
  __shared__ bf16 p_lds[4][2][16 * 72];
  const int tid = threadIdx.x;
  const int lane = tid & 63;
  const int w = tid >> 6;
  const int lr = lane & 15, lg = lane >> 4;
  const int n = blockIdx.x;
  const int xcd = n & 7;
  const int g = n >> 3;
  const int bh = xcd + 8 * (g & 3);
  const int rdec = g >> 2;
  const int qp = rdec & 15;
  const int split = rdec >> 4;
  const int qLb = qp * 64, qHb = (31 - qp) * 64;
  const int qL = qLb + w * 16;
  const int qH = qHb + w * 16;

  const bf16* Qp = qb + (size_t)bh * 2048 * 64;
  const bf16* Kp = kb + (size_t)bh * 2048 * 64;
  const bf16* Vp = vtb + (size_t)bh * 64 * 2048;

  bf16x8 qfL0 = *(const bf16x8*)&Qp[(size_t)(qL + lr) * 64 + lg * 8];
  bf16x8 qfL1 = *(const bf16x8*)&Qp[(size_t)(qL + lr) * 64 + 32 + lg * 8];
  bf16x8 qfH0 = *(const bf16x8*)&Qp[(size_t)(qH + lr) * 64 + lg * 8];
  bf16x8 qfH1 = *(const bf16x8*)&Qp[(size_t)(qH + lr) * 64 + 32 + lg * 8];

  f32x4 oL[4] = {}, oH[4] = {};
  f32x4 laccL = {}, laccH = {};
  bf16x8 ones;
#pragma unroll
  for (int j = 0; j < 8; ++j) ones[j] = (bf16)1.0f;

  bf16* plH = &p_lds[w][0][0];
  bf16* plL = &p_lds[w][1][0];

  const int sub = lane >> 3;
  const int gsw = ((lane & 7) ^ (sub & 7)) * 8;

#define STAGEKV(BB, TT)                                                        \
  do {                                                                         \
    _Pragma("unroll")                                                          \
    for (int j = 0; j < 2; ++j) {                                              \
      const int rb = j * 32 + w * 8;                                           \
      gl_lds16(Kp + (size_t)((TT) + rb + sub) * 64 + gsw, &Ks[BB][rb * 64]);   \
      gl_lds16(Vp + (size_t)(rb + sub) * 2048 + (TT) + gsw, &Vs[BB][rb * 64]); \
    }                                                                          \
  } while (0)

#define TILE8(T, r, gi) (*(const bf16x8*)&(T)[(r) * 64 + ((gi) ^ ((r) & 7)) * 8])

  const int t00 = split * 64;
  const int tmax = qHb + 64;
  STAGEKV(0, t00);
  int buf = 0;
  for (int t0 = t00; t0 < tmax; t0 += 128, buf ^= 1) {
    __syncthreads();
    if (t0 + 128 < tmax) STAGEKV(buf ^ 1, t0 + 128);
    const bf16* Kt = Ks[buf];
    const bf16* Vt = Vs[buf];
    const bool lact = (t0 <= qL + 15);
    const bool hmask = (t0 + 63 > qH);
    const bool lmask = (t0 + 63 > qL);

    f32x4 sH[4] = {}, sL[4] = {};
#pragma unroll
    for (int c = 0; c < 4; ++c) {
      bf16x8 kf0 = TILE8(Kt, c * 16 + lr, lg);
      bf16x8 kf1 = TILE8(Kt, c * 16 + lr, 4 + lg);
      sH[c] = MFMA16(qfH0, kf0, sH[c], 0, 0, 0);
      sH[c] = MFMA16(qfH1, kf1, sH[c], 0, 0, 0);
      if (lact) {
        sL[c] = MFMA16(qfL0, kf0, sL[c], 0, 0, 0);
        sL[c] = MFMA16(qfL1, kf1, sL[c], 0, 0, 0);
      }
    }
#pragma unroll
    for (int c = 0; c < 4; ++c)
#pragma unroll
      for (int rr = 0; rr < 4; ++rr) {
        const int t = t0 + c * 16 + lr;
        float v = sH[c][rr];
        if (hmask) v = (t <= qH + lg * 4 + rr) ? v : -1e30f;
        plH[(lg * 4 + rr) * 72 + c * 16 + lr] = (bf16)exp2f(v);
      }
    if (lact) {
#pragma unroll
      for (int c = 0; c < 4; ++c)
#pragma unroll
        for (int rr = 0; rr < 4; ++rr) {
          const int t = t0 + c * 16 + lr;
          float v = sL[c][rr];
          if (lmask) v = (t <= qL + lg * 4 + rr) ? v : -1e30f;
          plL[(lg * 4 + rr) * 72 + c * 16 + lr] = (bf16)exp2f(v);
        }
    }
    asm volatile("s_waitcnt lgkmcnt(0)" ::: "memory");
    __builtin_amdgcn_sched_barrier(0);
    bf16x8 paH0 = *(const bf16x8*)&plH[lr * 72 + lg * 8];
    bf16x8 paH1 = *(const bf16x8*)&plH[lr * 72 + 32 + lg * 8];
    bf16x8 paL0 = {}, paL1 = {};
    if (lact) {
      paL0 = *(const bf16x8*)&plL[lr * 72 + lg * 8];
      paL1 = *(const bf16x8*)&plL[lr * 72 + 32 + lg * 8];
    }
    __builtin_amdgcn_s_setprio(1);
    laccH = MFMA16(paH0, ones, laccH, 0, 0, 0);
    laccH = MFMA16(paH1, ones, laccH, 0, 0, 0);
    if (lact) {
      laccL = MFMA16(paL0, ones, laccL, 0, 0, 0);
      laccL = MFMA16(paL1, ones, laccL, 0, 0, 0);
    }
#pragma unroll
    for (int db = 0; db < 4; ++db) {
      bf16x8 vf0 = TILE8(Vt, db * 16 + lr, lg);
      bf16x8 vf1 = TILE8(Vt, db * 16 + lr, 4 + lg);
      oH[db] = MFMA16(paH0, vf0, oH[db], 0, 0, 0);
      oH[db] = MFMA16(paH1, vf1, oH[db], 0, 0, 0);
      if (lact) {
        oL[db] = MFMA16(paL0, vf0, oL[db], 0, 0, 0);
        oL[db] = MFMA16(paL1, vf1, oL[db], 0, 0, 0);
      }
    }
    __builtin_amdgcn_s_setprio(0);
  }
#undef STAGEKV
#undef TILE8

  bf16* opW = opart + ((size_t)split * 32 + bh) * 2048 * 64;
  float* lpW = lpart + ((size_t)split * 32 + bh) * 2048;
#pragma unroll
  for (int db = 0; db < 4; ++db)
#pragma unroll
    for (int rr = 0; rr < 4; ++rr) {
      opW[(size_t)(qL + lg * 4 + rr) * 64 + db * 16 + lr] = (bf16)oL[db][rr];
      opW[(size_t)(qH + lg * 4 + rr) * 64 + db * 16 + lr] = (bf16)oH[db][rr];
    }
  if (lr == 0) {
#pragma unroll
    for (int rr = 0; rr < 4; ++rr) {
      lpW[qL + lg * 4 + rr] = laccL[rr];
      lpW[qH + lg * 4 + rr] = laccH[rr];
    }
  }
}

// ---------------- PROVEN attention (round 6, 110 us) — runs after the
// experimental kernel and overwrites every opart/lpart element ---------------
__global__ __launch_bounds__(256, 4)
void attn_kernel(const bf16* __restrict__ qb, const bf16* __restrict__ kb,
                 const bf16* __restrict__ vtb,
                 bf16* __restrict__ opart, float* __restrict__ lpart) {
  __shared__ bf16 p_lds[4][2][16 * 40];
  const int tid = threadIdx.x;
  const int lane = tid & 63;
  const int w = tid >> 6;
  const int lr = lane & 15, lg = lane >> 4;
  const int n = blockIdx.x;
  const int xcd = n & 7;
  const int g = n >> 3;
  const int bh = xcd + 8 * (g & 3);
  const int rdec = g >> 2;
  const int qp = rdec & 15;
  const int split = rdec >> 4;
  const int qL = qp * 64 + w * 16;
  const int qH = (31 - qp) * 64 + w * 16;

  const bf16* Qp = qb + (size_t)bh * 2048 * 64;
  const bf16* Kp = kb + (size_t)bh * 2048 * 64;
  const bf16* Vp = vtb + (size_t)bh * 64 * 2048;

  bf16x8 qfL0 = *(const bf16x8*)&Qp[(size_t)(qL + lr) * 64 + lg * 8];
  bf16x8 qfL1 = *(const bf16x8*)&Qp[(size_t)(qL + lr) * 64 + 32 + lg * 8];
  bf16x8 qfH0 = *(const bf16x8*)&Qp[(size_t)(qH + lr) * 64 + lg * 8];
  bf16x8 qfH1 = *(const bf16x8*)&Qp[(size_t)(qH + lr) * 64 + 32 + lg * 8];

  f32x4 oL[4] = {}, oH[4] = {};
  f32x4 laccL = {}, laccH = {};
  bf16x8 ones;
#pragma unroll
  for (int j = 0; j < 8; ++j) ones[j] = (bf16)1.0f;

  bf16* plL = &p_lds[w][0][0];
  bf16* plH = &p_lds[w][1][0];
  const int endL = qL + 16, endH = qH + 16;

#define ATTN_STEP(QROW0, QF0, QF1, LACC, OACC, PL)                            \
  do {                                                                        \
    f32x4 s0 = {}, s1 = {};                                                   \
    s0 = MFMA16(QF0, kfA0, s0, 0, 0, 0);                                      \
    s0 = MFMA16(QF1, kfA1, s0, 0, 0, 0);                                      \
    s1 = MFMA16(QF0, kfB0, s1, 0, 0, 0);                                      \
    s1 = MFMA16(QF1, kfB1, s1, 0, 0, 0);                                      \
    if (t0 + 31 > (QROW0)) {                                                  \
      _Pragma("unroll")                                                       \
      for (int rr = 0; rr < 4; ++rr) {                                        \
        const int qrow = (QROW0) + lg * 4 + rr;                               \
        s0[rr] = (t0 + lr <= qrow) ? s0[rr] : -1e30f;                         \
        s1[rr] = (t0 + 16 + lr <= qrow) ? s1[rr] : -1e30f;                    \
      }                                                                       \
    }                                                                         \
    _Pragma("unroll")                                                         \
    for (int rr = 0; rr < 4; ++rr) {                                          \
      PL[(lg * 4 + rr) * 40 + lr] = (bf16)exp2f(s0[rr]);                      \
      PL[(lg * 4 + rr) * 40 + 16 + lr] = (bf16)exp2f(s1[rr]);                 \
    }                                                                         \
    asm volatile("s_waitcnt lgkmcnt(0)" ::: "memory");                        \
    bf16x8 pa = *(const bf16x8*)&PL[lr * 40 + lg * 8];                        \
    __builtin_amdgcn_s_setprio(1);                                            \
    LACC = MFMA16(pa, ones, LACC, 0, 0, 0);                                   \
    _Pragma("unroll")                                                         \
    for (int db = 0; db < 4; ++db)                                            \
      OACC[db] = MFMA16(pa, vfr[db], OACC[db], 0, 0, 0);                      \
    __builtin_amdgcn_s_setprio(0);                                            \
  } while (0)

  for (int t0 = split * 32; t0 < endH; t0 += 64) {
    const bf16* krA = &Kp[(size_t)(t0 + lr) * 64 + lg * 8];
    const bf16* krB = &Kp[(size_t)(t0 + 16 + lr) * 64 + lg * 8];
    bf16x8 kfA0 = *(const bf16x8*)(krA);
    bf16x8 kfA1 = *(const bf16x8*)(krA + 32);
    bf16x8 kfB0 = *(const bf16x8*)(krB);
    bf16x8 kfB1 = *(const bf16x8*)(krB + 32);
    bf16x8 vfr[4];
#pragma unroll
    for (int db = 0; db < 4; ++db)
      vfr[db] = *(const bf16x8*)&Vp[(size_t)(db * 16 + lr) * 2048 + t0 + lg * 8];

    ATTN_STEP(qH, qfH0, qfH1, laccH, oH, plH);
    if (t0 < endL) ATTN_STEP(qL, qfL0, qfL1, laccL, oL, plL);
  }
#undef ATTN_STEP

  bf16* opW = opart + ((size_t)split * 32 + bh) * 2048 * 64;
  float* lpW = lpart + ((size_t)split * 32 + bh) * 2048;
#pragma unroll
  for (int db = 0; db < 4; ++db)
#pragma unroll
    for (int rr = 0; rr < 4; ++rr) {
      opW[(size_t)(qL + lg * 4 + rr) * 64 + db * 16 + lr] = (bf16)oL[db][rr];
      opW[(size_t)(qH + lg * 4 + rr) * 64 + db * 16 + lr] = (bf16)oH[db][rr];
    }
  if (lr == 0) {
#pragma unroll
    for (int rr = 0; rr < 4; ++rr) {
      lpW[qL + lg * 4 + rr] = laccL[rr];
      lpW[qH + lg * 4 + rr] = laccH[rr];
    }
  }
}

// ---------------- split combine: a2 = (O0+O1)/(l0+l1) ----------------
__global__ void combine_kernel(const bf16* __restrict__ op, const float* __restrict__ lp,
                               bf16* __restrict__ a2) {
  const int idx = blockIdx.x * 256 + threadIdx.x;
  const int dq = idx & 15;
  const int s = (idx >> 4) & 2047;
  const int bh = idx >> 15;
  const size_t SPLIT_O = (size_t)32 * 2048 * 64;
  const size_t obase = ((size_t)bh * 2048 + s) * 64 + dq * 4;
  bf16x4 o0 = *(const bf16x4*)(op + obase);
  bf16x4 o1 = *(const bf16x4*)(op + SPLIT_O + obase);
  const float inv = 1.0f / (lp[bh * 2048 + s] + lp[32 * 2048 + bh * 2048 + s]);
  const int b = bh >> 4, h = bh & 15;
  bf16x4 r;
#pragma unroll
  for (int j = 0; j < 4; ++j)
    r[j] = (bf16)(((float)o0[j] + (float)o1[j]) * inv);
  *(bf16x4*)(a2 + ((size_t)b * 2048 + s) * 1024 + h * 64 + dq * 4) = r;
}

// ---------------- launch ----------------
extern "C" void kernel_launch(void* const* d_in, const int* in_sizes, int n_in,
                              void* d_out, int out_size, void* d_ws, size_t ws_size,
                              hipStream_t stream) {
  const float* x  = (const float*)d_in[0];
  const float* wq = (const float*)d_in[1];
  const float* bq = (const float*)d_in[2];
  const float* wk = (const float*)d_in[3];
  const float* bk = (const float*)d_in[4];
  const float* wv = (const float*)d_in[5];
  const float* bv = (const float*)d_in[6];
  const float* wp = (const float*)d_in[7];
  const float* bp = (const float*)d_in[8];
  float* out = (float*)d_out;

  char* ws = (char*)d_ws;
  const size_t MB = 1u << 20;
  bf16* xb     = (bf16*)(ws + 0 * MB);    // 8 MB (phase 1)
  bf16* wqkvT  = (bf16*)(ws + 8 * MB);    // 6 MB (phase 1)
  bf16* opart  = (bf16*)(ws + 0 * MB);    // 16 MB [2][32][2048][64] (phase 2)
  bf16* qb     = (bf16*)(ws + 16 * MB);   // 8 MB
  bf16* kb     = (bf16*)(ws + 24 * MB);   // 8 MB
  bf16* vtb    = (bf16*)(ws + 32 * MB);   // 8 MB
  bf16* a2     = (bf16*)(ws + 40 * MB);   // 8 MB
  bf16* wprojT = (bf16*)(ws + 48 * MB);   // 2 MB
  float* lpart = (float*)(ws + 50 * MB);  // 0.5 MB

  pack_x_kernel<<<dim3(4096), dim3(256), 0, stream>>>(x, xb, 4194304);
  pack_wqkv_kernel<<<dim3(16, 16, 3), dim3(256), 0, stream>>>(wq, wk, wv, wqkvT);
  pack_wproj_kernel<<<dim3(16, 16), dim3(256), 0, stream>>>(wp, wprojT);

  gemm_bt<0><<<dim3(24, 32), dim3(256), 0, stream>>>(
      xb, wqkvT, 4096, 3072, 1024, qb, kb, vtb, bq, bk, bv, (float*)nullptr, (const float*)nullptr);

  // EXPERIMENTAL first (timing/counters only) ...
  attn_stage_kernel<<<dim3(1024), dim3(256), 0, stream>>>(qb, kb, vtb, opart, lpart);
  // ... then the PROVEN kernel overwrites all of opart/lpart.
  attn_kernel<<<dim3(1024), dim3(256), 0, stream>>>(qb, kb, vtb, opart, lpart);
  combine_kernel<<<dim3(4096), dim3(256), 0, stream>>>(opart, lpart, a2);

  gemm_bt<1><<<dim3(8, 32), dim3(256), 0, stream>>>(
      a2, wprojT, 4096, 1024, 1024, (bf16*)nullptr, (bf16*)nullptr, (bf16*)nullptr,
      (const float*)nullptr, (const float*)nullptr, (const float*)nullptr, out, bp);
}

// Round 9
// 235.648 us; speedup vs baseline: 1.4101x; 1.4101x over previous
//
#include <hip/hip_runtime.h>

typedef __bf16 bf16;
typedef __bf16 bf16x4 __attribute__((ext_vector_type(4)));
typedef __bf16 bf16x8 __attribute__((ext_vector_type(8)));
typedef float f32x4 __attribute__((ext_vector_type(4)));

#define LOG2E 1.4426950408889634f
// folded into Q at pack time: score_in_log2_domain = (q.k) * 0.125 * LOG2E
#define QSCALE (0.125f * LOG2E)

__device__ __forceinline__ void gl_lds16(const bf16* g, bf16* l) {
  __builtin_amdgcn_global_load_lds(
      (const __attribute__((address_space(1))) void*)g,
      (__attribute__((address_space(3))) void*)l, 16, 0, 0);
}

#define MFMA16 __builtin_amdgcn_mfma_f32_16x16x32_bf16

// ---------------- pack kernels ----------------

__global__ void pack_x_kernel(const float* __restrict__ x, bf16* __restrict__ xb, int n) {
  int i = (blockIdx.x * 256 + threadIdx.x) * 4;
  if (i >= n) return;
  float4 v = *(const float4*)(x + i);
  xb[i + 0] = (bf16)v.x;
  xb[i + 1] = (bf16)v.y;
  xb[i + 2] = (bf16)v.z;
  xb[i + 3] = (bf16)v.w;
}

__global__ void pack_wqkv_kernel(const float* __restrict__ wq, const float* __restrict__ wk,
                                 const float* __restrict__ wv, bf16* __restrict__ wT) {
  __shared__ float tile[64][65];
  const int et = blockIdx.x;
  const int h  = blockIdx.y;
  const int p  = blockIdx.z;
  const float* src = (p == 0 ? wq : (p == 1 ? wk : wv)) + (size_t)h * 1024 * 64;
  const int tx = threadIdx.x & 63;
  const int ty = threadIdx.x >> 6;
  const int e0 = et * 64;
#pragma unroll
  for (int i = 0; i < 64; i += 4)
    tile[i + ty][tx] = src[(size_t)(e0 + i + ty) * 64 + tx];
  __syncthreads();
#pragma unroll
  for (int i = 0; i < 64; i += 4) {
    int d = i + ty;
    wT[((size_t)p * 1024 + h * 64 + d) * 1024 + e0 + tx] = (bf16)tile[tx][d];
  }
}

__global__ void pack_wproj_kernel(const float* __restrict__ wp, bf16* __restrict__ wT) {
  __shared__ float tile[64][65];
  const int ot = blockIdx.x, it = blockIdx.y;
  const int tx = threadIdx.x & 63;
  const int ty = threadIdx.x >> 6;
#pragma unroll
  for (int i = 0; i < 64; i += 4)
    tile[i + ty][tx] = wp[(size_t)(it * 64 + i + ty) * 1024 + ot * 64 + tx];
  __syncthreads();
#pragma unroll
  for (int i = 0; i < 64; i += 4) {
    int o = i + ty;
    wT[((size_t)ot * 64 + o) * 1024 + it * 64 + tx] = (bf16)tile[tx][o];
  }
}

// ---------------- GEMM: C[M,N] = A[M,K] * Bt[N,K]^T ----------------
template <int EPI>
__global__ __launch_bounds__(256, 2)
void gemm_bt(const bf16* __restrict__ A, const bf16* __restrict__ Bt,
             int M, int N, int K,
             bf16* qb, bf16* kb, bf16* vtb,
             const float* bq, const float* bk, const float* bv,
             float* outf, const float* bias) {
  __shared__ bf16 As[2][128 * 32];
  __shared__ bf16 Bs[2][128 * 32];
  const int tid = threadIdx.x;
  const int lane = tid & 63;
  const int w = tid >> 6;
  const int wm = w >> 1, wn = w & 1;
  const int m0 = blockIdx.y * 128, n0 = blockIdx.x * 128;
  const int r = tid >> 2;
  const int c = tid & 3;
  const int lr = lane & 15, lg = lane >> 4;

  f32x4 acc[4][4] = {};
  const bf16* Ar0 = A + (size_t)(m0 + r) * K + c * 8;
  const bf16* Ar1 = A + (size_t)(m0 + 64 + r) * K + c * 8;
  const bf16* Br0 = Bt + (size_t)(n0 + r) * K + c * 8;
  const bf16* Br1 = Bt + (size_t)(n0 + 64 + r) * K + c * 8;

#define STAGE(BUF, K0)                           \
  do {                                           \
    gl_lds16(Ar0 + (K0), &As[BUF][w * 512]);     \
    gl_lds16(Ar1 + (K0), &As[BUF][2048 + w * 512]); \
    gl_lds16(Br0 + (K0), &Bs[BUF][w * 512]);     \
    gl_lds16(Br1 + (K0), &Bs[BUF][2048 + w * 512]); \
  } while (0)

  STAGE(0, 0);
  int cur = 0;
  for (int k0 = 0; k0 < K; k0 += 32, cur ^= 1) {
    __syncthreads();
    if (k0 + 32 < K) STAGE(cur ^ 1, k0 + 32);
    bf16x8 af[4], bfr[4];
#pragma unroll
    for (int m = 0; m < 4; ++m)
      af[m] = *(const bf16x8*)&As[cur][(wm * 64 + m * 16 + lr) * 32 + lg * 8];
#pragma unroll
    for (int n = 0; n < 4; ++n)
      bfr[n] = *(const bf16x8*)&Bs[cur][(wn * 64 + n * 16 + lr) * 32 + lg * 8];
#pragma unroll
    for (int m = 0; m < 4; ++m)
#pragma unroll
      for (int n = 0; n < 4; ++n)
        acc[m][n] = MFMA16(af[m], bfr[n], acc[m][n], 0, 0, 0);
  }
#undef STAGE

#pragma unroll
  for (int m = 0; m < 4; ++m) {
    const int rowb = m0 + wm * 64 + m * 16 + lg * 4;
#pragma unroll
    for (int n = 0; n < 4; ++n) {
      const int col = n0 + wn * 64 + n * 16 + lr;
#pragma unroll
      for (int rr = 0; rr < 4; ++rr) {
        float v = acc[m][n][rr];
        const int rw = rowb + rr;
        if (EPI == 0) {
          const int p = col >> 10, rem = col & 1023;
          const int hh = rem >> 6, d = rem & 63;
          const int b = rw >> 11, s = rw & 2047;
          const size_t bhi = (size_t)(b * 16 + hh);
          if (p == 0)      qb[(bhi * 2048 + s) * 64 + d] = (bf16)((v + bq[rem]) * QSCALE);
          else if (p == 1) kb[(bhi * 2048 + s) * 64 + d] = (bf16)(v + bk[rem]);
          else             vtb[(bhi * 64 + d) * 2048 + s] = (bf16)(v + bv[rem]);
        } else {
          outf[(size_t)rw * N + col] = v + bias[col];
        }
      }
    }
  }
}

// ---------------- causal flash attention (LDS-staged, production) ----------
// Block = (qp, split, bh) via XCD-grouped decode; 4 waves; block-uniform
// t-loop; double-buffered K/V staging via global_load_lds with 16B-granule
// XOR swizzle (linear LDS dest + inverse-swizzled global source + same XOR
// on read — rule #21). sched_barrier(0) after the inline-asm lgkmcnt wait is
// REQUIRED (rule #18: MFMA hoists past inline-asm waits -> NaN without it).
__global__ __launch_bounds__(256, 3)
void attn_kernel(const bf16* __restrict__ qb, const bf16* __restrict__ kb,
                 const bf16* __restrict__ vtb,
                 bf16* __restrict__ opart, float* __restrict__ lpart) {
  __shared__ bf16 Ks[2][64 * 64];
  __shared__ bf16 Vs[2][64 * 64];
  __shared__ bf16 p_lds[4][2][16 * 72];
  const int tid = threadIdx.x;
  const int lane = tid & 63;
  const int w = tid >> 6;
  const int lr = lane & 15, lg = lane >> 4;
  // swizzled decode: xcd = n&7, bh = xcd + 8*(g&3) -> bh%8 == xcd
  const int n = blockIdx.x;
  const int xcd = n & 7;
  const int g = n >> 3;
  const int bh = xcd + 8 * (g & 3);
  const int rdec = g >> 2;
  const int qp = rdec & 15;
  const int split = rdec >> 4;
  const int qLb = qp * 64, qHb = (31 - qp) * 64;
  const int qL = qLb + w * 16;
  const int qH = qHb + w * 16;

  const bf16* Qp = qb + (size_t)bh * 2048 * 64;
  const bf16* Kp = kb + (size_t)bh * 2048 * 64;
  const bf16* Vp = vtb + (size_t)bh * 64 * 2048;

  bf16x8 qfL0 = *(const bf16x8*)&Qp[(size_t)(qL + lr) * 64 + lg * 8];
  bf16x8 qfL1 = *(const bf16x8*)&Qp[(size_t)(qL + lr) * 64 + 32 + lg * 8];
  bf16x8 qfH0 = *(const bf16x8*)&Qp[(size_t)(qH + lr) * 64 + lg * 8];
  bf16x8 qfH1 = *(const bf16x8*)&Qp[(size_t)(qH + lr) * 64 + 32 + lg * 8];

  f32x4 oL[4] = {}, oH[4] = {};
  f32x4 laccL = {}, laccH = {};
  bf16x8 ones;
#pragma unroll
  for (int j = 0; j < 8; ++j) ones[j] = (bf16)1.0f;

  bf16* plH = &p_lds[w][0][0];
  bf16* plL = &p_lds[w][1][0];

  // staging: lane l -> row sub = l>>3 within the wave's 8-row group,
  // granule p = l&7; source granule = p ^ (sub&7) (involution).
  const int sub = lane >> 3;
  const int gsw = ((lane & 7) ^ (sub & 7)) * 8;  // elems

#define STAGEKV(BB, TT)                                                        \
  do {                                                                         \
    _Pragma("unroll")                                                          \
    for (int j = 0; j < 2; ++j) {                                              \
      const int rb = j * 32 + w * 8;                                           \
      gl_lds16(Kp + (size_t)((TT) + rb + sub) * 64 + gsw, &Ks[BB][rb * 64]);   \
      gl_lds16(Vp + (size_t)(rb + sub) * 2048 + (TT) + gsw, &Vs[BB][rb * 64]); \
    }                                                                          \
  } while (0)

// swizzled 16B tile read: row r (0..63), granule gi (0..7)
#define TILE8(T, r, gi) (*(const bf16x8*)&(T)[(r) * 64 + ((gi) ^ ((r) & 7)) * 8])

  const int t00 = split * 64;
  const int tmax = qHb + 64;
  STAGEKV(0, t00);
  int buf = 0;
  for (int t0 = t00; t0 < tmax; t0 += 128, buf ^= 1) {
    __syncthreads();  // vmcnt drained at barrier: staged tile visible
    if (t0 + 128 < tmax) STAGEKV(buf ^ 1, t0 + 128);
    const bf16* Kt = Ks[buf];
    const bf16* Vt = Vs[buf];
    const bool lact = (t0 <= qL + 15);
    const bool hmask = (t0 + 63 > qH);
    const bool lmask = (t0 + 63 > qL);

    // QK^T: shared K fragments feed both H and L streams
    f32x4 sH[4] = {}, sL[4] = {};
#pragma unroll
    for (int c = 0; c < 4; ++c) {
      bf16x8 kf0 = TILE8(Kt, c * 16 + lr, lg);
      bf16x8 kf1 = TILE8(Kt, c * 16 + lr, 4 + lg);
      sH[c] = MFMA16(qfH0, kf0, sH[c], 0, 0, 0);
      sH[c] = MFMA16(qfH1, kf1, sH[c], 0, 0, 0);
      if (lact) {
        sL[c] = MFMA16(qfL0, kf0, sL[c], 0, 0, 0);
        sL[c] = MFMA16(qfL1, kf1, sL[c], 0, 0, 0);
      }
    }
    // mask + exp2 -> P tiles in LDS (transposed to A-fragment layout)
#pragma unroll
    for (int c = 0; c < 4; ++c)
#pragma unroll
      for (int rr = 0; rr < 4; ++rr) {
        const int t = t0 + c * 16 + lr;
        float v = sH[c][rr];
        if (hmask) v = (t <= qH + lg * 4 + rr) ? v : -1e30f;
        plH[(lg * 4 + rr) * 72 + c * 16 + lr] = (bf16)exp2f(v);
      }
    if (lact) {
#pragma unroll
      for (int c = 0; c < 4; ++c)
#pragma unroll
        for (int rr = 0; rr < 4; ++rr) {
          const int t = t0 + c * 16 + lr;
          float v = sL[c][rr];
          if (lmask) v = (t <= qL + lg * 4 + rr) ? v : -1e30f;
          plL[(lg * 4 + rr) * 72 + c * 16 + lr] = (bf16)exp2f(v);
        }
    }
    asm volatile("s_waitcnt lgkmcnt(0)" ::: "memory");
    __builtin_amdgcn_sched_barrier(0);  // rule #18: keep MFMA below the wait
    bf16x8 paH0 = *(const bf16x8*)&plH[lr * 72 + lg * 8];
    bf16x8 paH1 = *(const bf16x8*)&plH[lr * 72 + 32 + lg * 8];
    bf16x8 paL0 = {}, paL1 = {};
    if (lact) {
      paL0 = *(const bf16x8*)&plL[lr * 72 + lg * 8];
      paL1 = *(const bf16x8*)&plL[lr * 72 + 32 + lg * 8];
    }
    __builtin_amdgcn_s_setprio(1);
    laccH = MFMA16(paH0, ones, laccH, 0, 0, 0);
    laccH = MFMA16(paH1, ones, laccH, 0, 0, 0);
    if (lact) {
      laccL = MFMA16(paL0, ones, laccL, 0, 0, 0);
      laccL = MFMA16(paL1, ones, laccL, 0, 0, 0);
    }
#pragma unroll
    for (int db = 0; db < 4; ++db) {
      bf16x8 vf0 = TILE8(Vt, db * 16 + lr, lg);
      bf16x8 vf1 = TILE8(Vt, db * 16 + lr, 4 + lg);
      oH[db] = MFMA16(paH0, vf0, oH[db], 0, 0, 0);
      oH[db] = MFMA16(paH1, vf1, oH[db], 0, 0, 0);
      if (lact) {
        oL[db] = MFMA16(paL0, vf0, oL[db], 0, 0, 0);
        oL[db] = MFMA16(paL1, vf1, oL[db], 0, 0, 0);
      }
    }
    __builtin_amdgcn_s_setprio(0);
  }
#undef STAGEKV
#undef TILE8

  // epilogue: write unnormalized partials (always -> no poison survives)
  bf16* opW = opart + ((size_t)split * 32 + bh) * 2048 * 64;
  float* lpW = lpart + ((size_t)split * 32 + bh) * 2048;
#pragma unroll
  for (int db = 0; db < 4; ++db)
#pragma unroll
    for (int rr = 0; rr < 4; ++rr) {
      opW[(size_t)(qL + lg * 4 + rr) * 64 + db * 16 + lr] = (bf16)oL[db][rr];
      opW[(size_t)(qH + lg * 4 + rr) * 64 + db * 16 + lr] = (bf16)oH[db][rr];
    }
  if (lr == 0) {
#pragma unroll
    for (int rr = 0; rr < 4; ++rr) {
      lpW[qL + lg * 4 + rr] = laccL[rr];
      lpW[qH + lg * 4 + rr] = laccH[rr];
    }
  }
}

// ---------------- split combine: a2 = (O0+O1)/(l0+l1) ----------------
__global__ void combine_kernel(const bf16* __restrict__ op, const float* __restrict__ lp,
                               bf16* __restrict__ a2) {
  const int idx = blockIdx.x * 256 + threadIdx.x;
  const int dq = idx & 15;
  const int s = (idx >> 4) & 2047;
  const int bh = idx >> 15;
  const size_t SPLIT_O = (size_t)32 * 2048 * 64;
  const size_t obase = ((size_t)bh * 2048 + s) * 64 + dq * 4;
  bf16x4 o0 = *(const bf16x4*)(op + obase);
  bf16x4 o1 = *(const bf16x4*)(op + SPLIT_O + obase);
  const float inv = 1.0f / (lp[bh * 2048 + s] + lp[32 * 2048 + bh * 2048 + s]);
  const int b = bh >> 4, h = bh & 15;
  bf16x4 r;
#pragma unroll
  for (int j = 0; j < 4; ++j)
    r[j] = (bf16)(((float)o0[j] + (float)o1[j]) * inv);
  *(bf16x4*)(a2 + ((size_t)b * 2048 + s) * 1024 + h * 64 + dq * 4) = r;
}

// ---------------- launch ----------------
extern "C" void kernel_launch(void* const* d_in, const int* in_sizes, int n_in,
                              void* d_out, int out_size, void* d_ws, size_t ws_size,
                              hipStream_t stream) {
  const float* x  = (const float*)d_in[0];
  const float* wq = (const float*)d_in[1];
  const float* bq = (const float*)d_in[2];
  const float* wk = (const float*)d_in[3];
  const float* bk = (const float*)d_in[4];
  const float* wv = (const float*)d_in[5];
  const float* bv = (const float*)d_in[6];
  const float* wp = (const float*)d_in[7];
  const float* bp = (const float*)d_in[8];
  float* out = (float*)d_out;

  char* ws = (char*)d_ws;
  const size_t MB = 1u << 20;
  bf16* xb     = (bf16*)(ws + 0 * MB);    // 8 MB (phase 1)
  bf16* wqkvT  = (bf16*)(ws + 8 * MB);    // 6 MB (phase 1)
  bf16* opart  = (bf16*)(ws + 0 * MB);    // 16 MB [2][32][2048][64] (phase 2)
  bf16* qb     = (bf16*)(ws + 16 * MB);   // 8 MB
  bf16* kb     = (bf16*)(ws + 24 * MB);   // 8 MB
  bf16* vtb    = (bf16*)(ws + 32 * MB);   // 8 MB
  bf16* a2     = (bf16*)(ws + 40 * MB);   // 8 MB
  bf16* wprojT = (bf16*)(ws + 48 * MB);   // 2 MB
  float* lpart = (float*)(ws + 50 * MB);  // 0.5 MB

  pack_x_kernel<<<dim3(4096), dim3(256), 0, stream>>>(x, xb, 4194304);
  pack_wqkv_kernel<<<dim3(16, 16, 3), dim3(256), 0, stream>>>(wq, wk, wv, wqkvT);
  pack_wproj_kernel<<<dim3(16, 16), dim3(256), 0, stream>>>(wp, wprojT);

  gemm_bt<0><<<dim3(24, 32), dim3(256), 0, stream>>>(
      xb, wqkvT, 4096, 3072, 1024, qb, kb, vtb, bq, bk, bv, (float*)nullptr, (const float*)nullptr);

  attn_kernel<<<dim3(1024), dim3(256), 0, stream>>>(qb, kb, vtb, opart, lpart);
  combine_kernel<<<dim3(4096), dim3(256), 0, stream>>>(opart, lpart, a2);

  gemm_bt<1><<<dim3(8, 32), dim3(256), 0, stream>>>(
      a2, wprojT, 4096, 1024, 1024, (bf16*)nullptr, (bf16*)nullptr, (bf16*)nullptr,
      (const float*)nullptr, (const float*)nullptr, (const float*)nullptr, out, bp);
}

// Round 11
// 219.994 us; speedup vs baseline: 1.5105x; 1.0712x over previous
//
#include <hip/hip_runtime.h>

typedef __bf16 bf16;
typedef __bf16 bf16x4 __attribute__((ext_vector_type(4)));
typedef __bf16 bf16x8 __attribute__((ext_vector_type(8)));
typedef float f32x4 __attribute__((ext_vector_type(4)));

#define LOG2E 1.4426950408889634f
// folded into Q at pack time: score_in_log2_domain = (q.k) * 0.125 * LOG2E
#define QSCALE (0.125f * LOG2E)

__device__ __forceinline__ void gl_lds16(const bf16* g, bf16* l) {
  __builtin_amdgcn_global_load_lds(
      (const __attribute__((address_space(1))) void*)g,
      (__attribute__((address_space(3))) void*)l, 16, 0, 0);
}

#define MFMA16 __builtin_amdgcn_mfma_f32_16x16x32_bf16

// ---------------- pack kernels ----------------

__global__ void pack_x_kernel(const float* __restrict__ x, bf16* __restrict__ xb, int n) {
  int i = (blockIdx.x * 256 + threadIdx.x) * 4;
  if (i >= n) return;
  float4 v = *(const float4*)(x + i);
  xb[i + 0] = (bf16)v.x;
  xb[i + 1] = (bf16)v.y;
  xb[i + 2] = (bf16)v.z;
  xb[i + 3] = (bf16)v.w;
}

__global__ void pack_wqkv_kernel(const float* __restrict__ wq, const float* __restrict__ wk,
                                 const float* __restrict__ wv, bf16* __restrict__ wT) {
  __shared__ float tile[64][65];
  const int et = blockIdx.x;
  const int h  = blockIdx.y;
  const int p  = blockIdx.z;
  const float* src = (p == 0 ? wq : (p == 1 ? wk : wv)) + (size_t)h * 1024 * 64;
  const int tx = threadIdx.x & 63;
  const int ty = threadIdx.x >> 6;
  const int e0 = et * 64;
#pragma unroll
  for (int i = 0; i < 64; i += 4)
    tile[i + ty][tx] = src[(size_t)(e0 + i + ty) * 64 + tx];
  __syncthreads();
#pragma unroll
  for (int i = 0; i < 64; i += 4) {
    int d = i + ty;
    wT[((size_t)p * 1024 + h * 64 + d) * 1024 + e0 + tx] = (bf16)tile[tx][d];
  }
}

__global__ void pack_wproj_kernel(const float* __restrict__ wp, bf16* __restrict__ wT) {
  __shared__ float tile[64][65];
  const int ot = blockIdx.x, it = blockIdx.y;
  const int tx = threadIdx.x & 63;
  const int ty = threadIdx.x >> 6;
#pragma unroll
  for (int i = 0; i < 64; i += 4)
    tile[i + ty][tx] = wp[(size_t)(it * 64 + i + ty) * 1024 + ot * 64 + tx];
  __syncthreads();
#pragma unroll
  for (int i = 0; i < 64; i += 4) {
    int o = i + ty;
    wT[((size_t)ot * 64 + o) * 1024 + it * 64 + tx] = (bf16)tile[tx][o];
  }
}

// ---------------- GEMM (128x128): QKV projection ----------------
// launch_bounds(256,3): grid 24x32=768 = exactly 3 blocks/CU -> single
// dispatch round (was 2/CU -> 1.5 rounds, 33% tail).
__global__ __launch_bounds__(256, 3)
void gemm_qkv(const bf16* __restrict__ A, const bf16* __restrict__ Bt,
              int M, int N, int K,
              bf16* qb, bf16* kb, bf16* vtb,
              const float* bq, const float* bk, const float* bv) {
  __shared__ bf16 As[2][128 * 32];
  __shared__ bf16 Bs[2][128 * 32];
  const int tid = threadIdx.x;
  const int lane = tid & 63;
  const int w = tid >> 6;
  const int wm = w >> 1, wn = w & 1;
  const int m0 = blockIdx.y * 128, n0 = blockIdx.x * 128;
  const int r = tid >> 2;
  const int c = tid & 3;
  const int lr = lane & 15, lg = lane >> 4;

  f32x4 acc[4][4] = {};
  const bf16* Ar0 = A + (size_t)(m0 + r) * K + c * 8;
  const bf16* Ar1 = A + (size_t)(m0 + 64 + r) * K + c * 8;
  const bf16* Br0 = Bt + (size_t)(n0 + r) * K + c * 8;
  const bf16* Br1 = Bt + (size_t)(n0 + 64 + r) * K + c * 8;

#define STAGE(BUF, K0)                           \
  do {                                           \
    gl_lds16(Ar0 + (K0), &As[BUF][w * 512]);     \
    gl_lds16(Ar1 + (K0), &As[BUF][2048 + w * 512]); \
    gl_lds16(Br0 + (K0), &Bs[BUF][w * 512]);     \
    gl_lds16(Br1 + (K0), &Bs[BUF][2048 + w * 512]); \
  } while (0)

  STAGE(0, 0);
  int cur = 0;
  for (int k0 = 0; k0 < K; k0 += 32, cur ^= 1) {
    __syncthreads();
    if (k0 + 32 < K) STAGE(cur ^ 1, k0 + 32);
    bf16x8 af[4], bfr[4];
#pragma unroll
    for (int m = 0; m < 4; ++m)
      af[m] = *(const bf16x8*)&As[cur][(wm * 64 + m * 16 + lr) * 32 + lg * 8];
#pragma unroll
    for (int n = 0; n < 4; ++n)
      bfr[n] = *(const bf16x8*)&Bs[cur][(wn * 64 + n * 16 + lr) * 32 + lg * 8];
#pragma unroll
    for (int m = 0; m < 4; ++m)
#pragma unroll
      for (int n = 0; n < 4; ++n)
        acc[m][n] = MFMA16(af[m], bfr[n], acc[m][n], 0, 0, 0);
  }
#undef STAGE

#pragma unroll
  for (int m = 0; m < 4; ++m) {
    const int rowb = m0 + wm * 64 + m * 16 + lg * 4;
#pragma unroll
    for (int n = 0; n < 4; ++n) {
      const int col = n0 + wn * 64 + n * 16 + lr;
#pragma unroll
      for (int rr = 0; rr < 4; ++rr) {
        float v = acc[m][n][rr];
        const int rw = rowb + rr;
        const int p = col >> 10, rem = col & 1023;
        const int hh = rem >> 6, d = rem & 63;
        const int b = rw >> 11, s = rw & 2047;
        const size_t bhi = (size_t)(b * 16 + hh);
        if (p == 0)      qb[(bhi * 2048 + s) * 64 + d] = (bf16)((v + bq[rem]) * QSCALE);
        else if (p == 1) kb[(bhi * 2048 + s) * 64 + d] = (bf16)(v + bk[rem]);
        else             vtb[(bhi * 64 + d) * 2048 + s] = (bf16)(v + bv[rem]);
      }
    }
  }
}

// ---------------- GEMM (128x64): output projection ----------------
// BN=64 -> grid 16x32 = 512 blocks (vs 256 at BN=128 = 1/CU, latency-starved).
// Waves 2Mx2N, each 64x32; 24 KB LDS; launch_bounds(256,4) -> 4 blocks/CU.
__global__ __launch_bounds__(256, 4)
void gemm_out(const bf16* __restrict__ A, const bf16* __restrict__ Bt,
              int M, int N, int K,
              float* __restrict__ outf, const float* __restrict__ bias) {
  __shared__ bf16 As[2][128 * 32];
  __shared__ bf16 Bs[2][64 * 32];
  const int tid = threadIdx.x;
  const int lane = tid & 63;
  const int w = tid >> 6;
  const int wm = w >> 1, wn = w & 1;
  const int m0 = blockIdx.y * 128, n0 = blockIdx.x * 64;
  const int r = tid >> 2;
  const int c = tid & 3;
  const int lr = lane & 15, lg = lane >> 4;

  f32x4 acc[4][2] = {};
  const bf16* Ar0 = A + (size_t)(m0 + r) * K + c * 8;
  const bf16* Ar1 = A + (size_t)(m0 + 64 + r) * K + c * 8;
  const bf16* Br0 = Bt + (size_t)(n0 + r) * K + c * 8;

#define STAGE(BUF, K0)                              \
  do {                                              \
    gl_lds16(Ar0 + (K0), &As[BUF][w * 512]);        \
    gl_lds16(Ar1 + (K0), &As[BUF][2048 + w * 512]); \
    gl_lds16(Br0 + (K0), &Bs[BUF][w * 512]);        \
  } while (0)

  STAGE(0, 0);
  int cur = 0;
  for (int k0 = 0; k0 < K; k0 += 32, cur ^= 1) {
    __syncthreads();
    if (k0 + 32 < K) STAGE(cur ^ 1, k0 + 32);
    bf16x8 af[4], bfr[2];
#pragma unroll
    for (int m = 0; m < 4; ++m)
      af[m] = *(const bf16x8*)&As[cur][(wm * 64 + m * 16 + lr) * 32 + lg * 8];
#pragma unroll
    for (int n = 0; n < 2; ++n)
      bfr[n] = *(const bf16x8*)&Bs[cur][(wn * 32 + n * 16 + lr) * 32 + lg * 8];
#pragma unroll
    for (int m = 0; m < 4; ++m)
#pragma unroll
      for (int n = 0; n < 2; ++n)
        acc[m][n] = MFMA16(af[m], bfr[n], acc[m][n], 0, 0, 0);
  }
#undef STAGE

#pragma unroll
  for (int m = 0; m < 4; ++m) {
    const int rowb = m0 + wm * 64 + m * 16 + lg * 4;
#pragma unroll
    for (int n = 0; n < 2; ++n) {
      const int col = n0 + wn * 32 + n * 16 + lr;
#pragma unroll
      for (int rr = 0; rr < 4; ++rr)
        outf[(size_t)(rowb + rr) * N + col] = acc[m][n][rr] + bias[col];
    }
  }
}

// ---------------- causal flash attention (LDS-staged, production) ----------
// Block = (qp, split, bh) via XCD-grouped decode; 4 waves; block-uniform
// t-loop; double-buffered K/V staging via global_load_lds with 16B-granule
// XOR swizzle (linear LDS dest + inverse-swizzled global source + same XOR
// on read — rule #21). sched_barrier(0) after the inline-asm lgkmcnt wait is
// REQUIRED (rule #18: MFMA hoists past inline-asm waits -> NaN without it).
__global__ __launch_bounds__(256, 3)
void attn_kernel(const bf16* __restrict__ qb, const bf16* __restrict__ kb,
                 const bf16* __restrict__ vtb,
                 bf16* __restrict__ opart, float* __restrict__ lpart) {
  __shared__ bf16 Ks[2][64 * 64];
  __shared__ bf16 Vs[2][64 * 64];
  __shared__ bf16 p_lds[4][2][16 * 72];
  const int tid = threadIdx.x;
  const int lane = tid & 63;
  const int w = tid >> 6;
  const int lr = lane & 15, lg = lane >> 4;
  const int n = blockIdx.x;
  const int xcd = n & 7;
  const int g = n >> 3;
  const int bh = xcd + 8 * (g & 3);
  const int rdec = g >> 2;
  const int qp = rdec & 15;
  const int split = rdec >> 4;
  const int qLb = qp * 64, qHb = (31 - qp) * 64;
  const int qL = qLb + w * 16;
  const int qH = qHb + w * 16;

  const bf16* Qp = qb + (size_t)bh * 2048 * 64;
  const bf16* Kp = kb + (size_t)bh * 2048 * 64;
  const bf16* Vp = vtb + (size_t)bh * 64 * 2048;

  bf16x8 qfL0 = *(const bf16x8*)&Qp[(size_t)(qL + lr) * 64 + lg * 8];
  bf16x8 qfL1 = *(const bf16x8*)&Qp[(size_t)(qL + lr) * 64 + 32 + lg * 8];
  bf16x8 qfH0 = *(const bf16x8*)&Qp[(size_t)(qH + lr) * 64 + lg * 8];
  bf16x8 qfH1 = *(const bf16x8*)&Qp[(size_t)(qH + lr) * 64 + 32 + lg * 8];

  f32x4 oL[4] = {}, oH[4] = {};
  f32x4 laccL = {}, laccH = {};
  bf16x8 ones;
#pragma unroll
  for (int j = 0; j < 8; ++j) ones[j] = (bf16)1.0f;

  bf16* plH = &p_lds[w][0][0];
  bf16* plL = &p_lds[w][1][0];

  const int sub = lane >> 3;
  const int gsw = ((lane & 7) ^ (sub & 7)) * 8;  // elems

#define STAGEKV(BB, TT)                                                        \
  do {                                                                         \
    _Pragma("unroll")                                                          \
    for (int j = 0; j < 2; ++j) {                                              \
      const int rb = j * 32 + w * 8;                                           \
      gl_lds16(Kp + (size_t)((TT) + rb + sub) * 64 + gsw, &Ks[BB][rb * 64]);   \
      gl_lds16(Vp + (size_t)(rb + sub) * 2048 + (TT) + gsw, &Vs[BB][rb * 64]); \
    }                                                                          \
  } while (0)

#define TILE8(T, r, gi) (*(const bf16x8*)&(T)[(r) * 64 + ((gi) ^ ((r) & 7)) * 8])

  const int t00 = split * 64;
  const int tmax = qHb + 64;
  STAGEKV(0, t00);
  int buf = 0;
  for (int t0 = t00; t0 < tmax; t0 += 128, buf ^= 1) {
    __syncthreads();  // vmcnt drained at barrier: staged tile visible
    if (t0 + 128 < tmax) STAGEKV(buf ^ 1, t0 + 128);
    const bf16* Kt = Ks[buf];
    const bf16* Vt = Vs[buf];
    const bool lact = (t0 <= qL + 15);
    const bool hmask = (t0 + 63 > qH);
    const bool lmask = (t0 + 63 > qL);

    f32x4 sH[4] = {}, sL[4] = {};
#pragma unroll
    for (int c = 0; c < 4; ++c) {
      bf16x8 kf0 = TILE8(Kt, c * 16 + lr, lg);
      bf16x8 kf1 = TILE8(Kt, c * 16 + lr, 4 + lg);
      sH[c] = MFMA16(qfH0, kf0, sH[c], 0, 0, 0);
      sH[c] = MFMA16(qfH1, kf1, sH[c], 0, 0, 0);
      if (lact) {
        sL[c] = MFMA16(qfL0, kf0, sL[c], 0, 0, 0);
        sL[c] = MFMA16(qfL1, kf1, sL[c], 0, 0, 0);
      }
    }
#pragma unroll
    for (int c = 0; c < 4; ++c)
#pragma unroll
      for (int rr = 0; rr < 4; ++rr) {
        const int t = t0 + c * 16 + lr;
        float v = sH[c][rr];
        if (hmask) v = (t <= qH + lg * 4 + rr) ? v : -1e30f;
        plH[(lg * 4 + rr) * 72 + c * 16 + lr] = (bf16)exp2f(v);
      }
    if (lact) {
#pragma unroll
      for (int c = 0; c < 4; ++c)
#pragma unroll
        for (int rr = 0; rr < 4; ++rr) {
          const int t = t0 + c * 16 + lr;
          float v = sL[c][rr];
          if (lmask) v = (t <= qL + lg * 4 + rr) ? v : -1e30f;
          plL[(lg * 4 + rr) * 72 + c * 16 + lr] = (bf16)exp2f(v);
        }
    }
    asm volatile("s_waitcnt lgkmcnt(0)" ::: "memory");
    __builtin_amdgcn_sched_barrier(0);  // rule #18: keep MFMA below the wait
    bf16x8 paH0 = *(const bf16x8*)&plH[lr * 72 + lg * 8];
    bf16x8 paH1 = *(const bf16x8*)&plH[lr * 72 + 32 + lg * 8];
    bf16x8 paL0 = {}, paL1 = {};
    if (lact) {
      paL0 = *(const bf16x8*)&plL[lr * 72 + lg * 8];
      paL1 = *(const bf16x8*)&plL[lr * 72 + 32 + lg * 8];
    }
    __builtin_amdgcn_s_setprio(1);
    laccH = MFMA16(paH0, ones, laccH, 0, 0, 0);
    laccH = MFMA16(paH1, ones, laccH, 0, 0, 0);
    if (lact) {
      laccL = MFMA16(paL0, ones, laccL, 0, 0, 0);
      laccL = MFMA16(paL1, ones, laccL, 0, 0, 0);
    }
#pragma unroll
    for (int db = 0; db < 4; ++db) {
      bf16x8 vf0 = TILE8(Vt, db * 16 + lr, lg);
      bf16x8 vf1 = TILE8(Vt, db * 16 + lr, 4 + lg);
      oH[db] = MFMA16(paH0, vf0, oH[db], 0, 0, 0);
      oH[db] = MFMA16(paH1, vf1, oH[db], 0, 0, 0);
      if (lact) {
        oL[db] = MFMA16(paL0, vf0, oL[db], 0, 0, 0);
        oL[db] = MFMA16(paL1, vf1, oL[db], 0, 0, 0);
      }
    }
    __builtin_amdgcn_s_setprio(0);
  }
#undef STAGEKV
#undef TILE8

  bf16* opW = opart + ((size_t)split * 32 + bh) * 2048 * 64;
  float* lpW = lpart + ((size_t)split * 32 + bh) * 2048;
#pragma unroll
  for (int db = 0; db < 4; ++db)
#pragma unroll
    for (int rr = 0; rr < 4; ++rr) {
      opW[(size_t)(qL + lg * 4 + rr) * 64 + db * 16 + lr] = (bf16)oL[db][rr];
      opW[(size_t)(qH + lg * 4 + rr) * 64 + db * 16 + lr] = (bf16)oH[db][rr];
    }
  if (lr == 0) {
#pragma unroll
    for (int rr = 0; rr < 4; ++rr) {
      lpW[qL + lg * 4 + rr] = laccL[rr];
      lpW[qH + lg * 4 + rr] = laccH[rr];
    }
  }
}

// ---------------- split combine: a2 = (O0+O1)/(l0+l1) ----------------
__global__ void combine_kernel(const bf16* __restrict__ op, const float* __restrict__ lp,
                               bf16* __restrict__ a2) {
  const int idx = blockIdx.x * 256 + threadIdx.x;
  const int dq = idx & 15;
  const int s = (idx >> 4) & 2047;
  const int bh = idx >> 15;
  const size_t SPLIT_O = (size_t)32 * 2048 * 64;
  const size_t obase = ((size_t)bh * 2048 + s) * 64 + dq * 4;
  bf16x4 o0 = *(const bf16x4*)(op + obase);
  bf16x4 o1 = *(const bf16x4*)(op + SPLIT_O + obase);
  const float inv = 1.0f / (lp[bh * 2048 + s] + lp[32 * 2048 + bh * 2048 + s]);
  const int b = bh >> 4, h = bh & 15;
  bf16x4 r;
#pragma unroll
  for (int j = 0; j < 4; ++j)
    r[j] = (bf16)(((float)o0[j] + (float)o1[j]) * inv);
  *(bf16x4*)(a2 + ((size_t)b * 2048 + s) * 1024 + h * 64 + dq * 4) = r;
}

// ---------------- launch ----------------
extern "C" void kernel_launch(void* const* d_in, const int* in_sizes, int n_in,
                              void* d_out, int out_size, void* d_ws, size_t ws_size,
                              hipStream_t stream) {
  const float* x  = (const float*)d_in[0];
  const float* wq = (const float*)d_in[1];
  const float* bq = (const float*)d_in[2];
  const float* wk = (const float*)d_in[3];
  const float* bk = (const float*)d_in[4];
  const float* wv = (const float*)d_in[5];
  const float* bv = (const float*)d_in[6];
  const float* wp = (const float*)d_in[7];
  const float* bp = (const float*)d_in[8];
  float* out = (float*)d_out;

  char* ws = (char*)d_ws;
  const size_t MB = 1u << 20;
  bf16* xb     = (bf16*)(ws + 0 * MB);    // 8 MB (phase 1)
  bf16* wqkvT  = (bf16*)(ws + 8 * MB);    // 6 MB (phase 1)
  bf16* opart  = (bf16*)(ws + 0 * MB);    // 16 MB [2][32][2048][64] (phase 2)
  bf16* qb     = (bf16*)(ws + 16 * MB);   // 8 MB
  bf16* kb     = (bf16*)(ws + 24 * MB);   // 8 MB
  bf16* vtb    = (bf16*)(ws + 32 * MB);   // 8 MB
  bf16* a2     = (bf16*)(ws + 40 * MB);   // 8 MB
  bf16* wprojT = (bf16*)(ws + 48 * MB);   // 2 MB
  float* lpart = (float*)(ws + 50 * MB);  // 0.5 MB

  pack_x_kernel<<<dim3(4096), dim3(256), 0, stream>>>(x, xb, 4194304);
  pack_wqkv_kernel<<<dim3(16, 16, 3), dim3(256), 0, stream>>>(wq, wk, wv, wqkvT);
  pack_wproj_kernel<<<dim3(16, 16), dim3(256), 0, stream>>>(wp, wprojT);

  gemm_qkv<<<dim3(24, 32), dim3(256), 0, stream>>>(
      xb, wqkvT, 4096, 3072, 1024, qb, kb, vtb, bq, bk, bv);

  attn_kernel<<<dim3(1024), dim3(256), 0, stream>>>(qb, kb, vtb, opart, lpart);
  combine_kernel<<<dim3(4096), dim3(256), 0, stream>>>(opart, lpart, a2);

  gemm_out<<<dim3(16, 32), dim3(256), 0, stream>>>(
      a2, wprojT, 4096, 1024, 1024, out, bp);
}